// Round 1
// baseline (4278.311 us; speedup 1.0000x reference)
//
#include <hip/hip_runtime.h>

#define BATCH 2048
#define RES   7
#define NPOS  49
#define CDIM  512
#define HEADS 4
#define KD    32
#define DDIM  128
#define QO    192
#define EPS   1e-5f
#define KPAD  33
#define HPAD  516   // 516 % 32 == 4, rows 16B-aligned; reads are broadcast so banks don't matter

// ---------------------------------------------------------------------------
// Kernel 1: cascaded group attention. One block per batch element.
// Writes RAW (pre-relu) head outputs into d_out at h[b][n][head*128+d];
// kernel 2 consumes them in place.
// ---------------------------------------------------------------------------
__global__ __launch_bounds__(256) void cga_attn_kernel(
    const float* __restrict__ x,
    const float* __restrict__ qkv_w,
    const float* __restrict__ qkv_g, const float* __restrict__ qkv_bb,
    const float* __restrict__ qkv_m, const float* __restrict__ qkv_v,
    const float* __restrict__ dw_w,
    const float* __restrict__ dw_g, const float* __restrict__ dw_bb,
    const float* __restrict__ dw_m, const float* __restrict__ dw_v,
    const float* __restrict__ attn_bias,
    const int*   __restrict__ bias_idxs,
    float* __restrict__ hout)
{
    __shared__ float feat[NPOS * DDIM];   // 25088 B
    __shared__ float qb  [NPOS * KD];     //  6272 B
    __shared__ float kb  [NPOS * KPAD];   //  6468 B (padded: QK^T reads k[m][j] across m)
    __shared__ float vb  [NPOS * DDIM];   // 25088 B
    __shared__ float qc  [NPOS * KD];     //  6272 B
    __shared__ float att [NPOS * NPOS];   //  9604 B   -> total 78792 B, 2 blocks/CU

    const int b   = blockIdx.x;
    const int tid = threadIdx.x;
    const float scale = 0.17677669529663687f;   // 32^-0.5
    const float* xb = x    + (size_t)b * NPOS * CDIM;
    float*       hb = hout + (size_t)b * NPOS * CDIM;

    for (int head = 0; head < HEADS; ++head) {
        // ---- feat = (head==0 ? chunk0 : prev_out + chunk_head)
        for (int idx = tid; idx < NPOS * DDIM; idx += 256) {
            int n = idx >> 7, c = idx & 127;
            float xv = xb[n * CDIM + head * DDIM + c];
            feat[idx] = (head == 0) ? xv : feat[idx] + xv;
        }
        __syncthreads();

        // ---- y = feat @ qkv_w[head]^T, BN fused. One output channel per thread;
        //      weight row streamed once (registers), feat rows are LDS broadcasts.
        if (tid < QO) {
            const int o = tid;
            const float4* wr = (const float4*)(qkv_w + (size_t)(head * QO + o) * DDIM);
            float acc[NPOS];
            #pragma unroll
            for (int n = 0; n < NPOS; ++n) acc[n] = 0.f;
            for (int d4 = 0; d4 < DDIM / 4; ++d4) {
                float4 w = wr[d4];
                #pragma unroll
                for (int n = 0; n < NPOS; ++n) {
                    float4 f = *(const float4*)(feat + n * DDIM + d4 * 4);
                    acc[n] += f.x * w.x + f.y * w.y + f.z * w.z + f.w * w.w;
                }
            }
            float s = qkv_g[head * QO + o] * rsqrtf(qkv_v[head * QO + o] + EPS);
            float t = qkv_bb[head * QO + o] - qkv_m[head * QO + o] * s;
            #pragma unroll
            for (int n = 0; n < NPOS; ++n) {
                float yv = acc[n] * s + t;
                if (o < KD)            qb[n * KD   + o]          = yv;
                else if (o < 2 * KD)   kb[n * KPAD + (o - KD)]   = yv;
                else                   vb[n * DDIM + (o - 2*KD)] = yv;
            }
        }
        __syncthreads();

        // ---- depthwise 5x5 SAME conv on q (per channel) + BN
        for (int idx = tid; idx < NPOS * KD; idx += 256) {
            int n = idx >> 5, ch = idx & 31;
            int r = n / RES, c0 = n - r * RES;
            const float* wd = dw_w + (size_t)(head * KD + ch) * 25;
            float acc = 0.f;
            #pragma unroll
            for (int dy = 0; dy < 5; ++dy) {
                int ry = r + dy - 2;
                if (ry < 0 || ry >= RES) continue;
                #pragma unroll
                for (int dx = 0; dx < 5; ++dx) {
                    int cx = c0 + dx - 2;
                    if (cx < 0 || cx >= RES) continue;
                    acc += qb[(ry * RES + cx) * KD + ch] * wd[dy * 5 + dx];
                }
            }
            float s = dw_g[head * KD + ch] * rsqrtf(dw_v[head * KD + ch] + EPS);
            float t = dw_bb[head * KD + ch] - dw_m[head * KD + ch] * s;
            qc[idx] = acc * s + t;
        }
        __syncthreads();

        // ---- scores = qc @ k^T * scale + bias
        for (int idx = tid; idx < NPOS * NPOS; idx += 256) {
            int n = idx / NPOS, m = idx - n * NPOS;
            float acc = 0.f;
            #pragma unroll
            for (int j = 0; j < KD; ++j) acc += qc[n * KD + j] * kb[m * KPAD + j];
            att[idx] = acc * scale + attn_bias[head * NPOS + bias_idxs[idx]];
        }
        __syncthreads();

        // ---- softmax, one row per thread (49 active)
        if (tid < NPOS) {
            float mx = -1e30f;
            for (int m = 0; m < NPOS; ++m) mx = fmaxf(mx, att[tid * NPOS + m]);
            float sm = 0.f;
            for (int m = 0; m < NPOS; ++m) {
                float e = __expf(att[tid * NPOS + m] - mx);
                att[tid * NPOS + m] = e;
                sm += e;
            }
            float inv = 1.f / sm;
            for (int m = 0; m < NPOS; ++m) att[tid * NPOS + m] *= inv;
        }
        __syncthreads();

        // ---- out = att @ v → feat (cascade input) and global h (raw)
        for (int idx = tid; idx < NPOS * (DDIM / 4); idx += 256) {
            int n = idx >> 5, d4 = idx & 31;
            float4 acc = {0.f, 0.f, 0.f, 0.f};
            for (int m = 0; m < NPOS; ++m) {
                float a = att[n * NPOS + m];
                float4 v4 = *(const float4*)(vb + m * DDIM + d4 * 4);
                acc.x += a * v4.x; acc.y += a * v4.y;
                acc.z += a * v4.z; acc.w += a * v4.w;
            }
            *(float4*)(feat + n * DDIM + d4 * 4) = acc;
            *(float4*)(hb + n * CDIM + head * DDIM + d4 * 4) = acc;
        }
        __syncthreads();
    }
}

// ---------------------------------------------------------------------------
// Kernel 2: out = BN(relu(h) @ proj_w^T), in place on d_out.
// One block per batch. relu(h) staged once in LDS; every hs read is a
// same-address wave broadcast; each weight float4 is reused 13x in registers.
// ---------------------------------------------------------------------------
__global__ __launch_bounds__(256) void cga_proj_kernel(
    const float* __restrict__ proj_w,
    const float* __restrict__ proj_g, const float* __restrict__ proj_bb,
    const float* __restrict__ proj_m, const float* __restrict__ proj_v,
    float* __restrict__ io)
{
    __shared__ float hs[NPOS * HPAD];   // 101136 B -> 1 block/CU

    const int b   = blockIdx.x;
    const int tid = threadIdx.x;
    float* ob = io + (size_t)b * NPOS * CDIM;

    // stage relu(h)
    for (int idx = tid; idx < NPOS * (CDIM / 4); idx += 256) {
        int n = idx >> 7, d4 = idx & 127;
        float4 v = *(const float4*)(ob + n * CDIM + d4 * 4);
        v.x = fmaxf(v.x, 0.f); v.y = fmaxf(v.y, 0.f);
        v.z = fmaxf(v.z, 0.f); v.w = fmaxf(v.w, 0.f);
        *(float4*)(hs + n * HPAD + d4 * 4) = v;
    }
    __syncthreads();

    const int wave  = tid >> 6;
    const int lane  = tid & 63;
    const int n0    = wave * 13;
    const int ncnt  = (wave == 3) ? 10 : 13;   // 13+13+13+10 = 49
    const int obase = lane * 8;                // 64 lanes x 8 = 512 channels

    float acc[8][13];
    #pragma unroll
    for (int oi = 0; oi < 8; ++oi)
        #pragma unroll
        for (int ni = 0; ni < 13; ++ni) acc[oi][ni] = 0.f;

    for (int d4 = 0; d4 < CDIM / 4; ++d4) {
        float4 w[8];
        #pragma unroll
        for (int oi = 0; oi < 8; ++oi)
            w[oi] = *(const float4*)(proj_w + (size_t)(obase + oi) * CDIM + d4 * 4);
        #pragma unroll
        for (int ni = 0; ni < 13; ++ni) {
            if (ni < ncnt) {   // wave-uniform guard
                float4 h4 = *(const float4*)(hs + (n0 + ni) * HPAD + d4 * 4);
                #pragma unroll
                for (int oi = 0; oi < 8; ++oi)
                    acc[oi][ni] += h4.x * w[oi].x + h4.y * w[oi].y
                                 + h4.z * w[oi].z + h4.w * w[oi].w;
            }
        }
    }

    float s[8], t[8];
    #pragma unroll
    for (int oi = 0; oi < 8; ++oi) {
        int o = obase + oi;
        s[oi] = proj_g[o] * rsqrtf(proj_v[o] + EPS);
        t[oi] = proj_bb[o] - proj_m[o] * s[oi];
    }
    for (int ni = 0; ni < ncnt; ++ni) {
        int n = n0 + ni;
        #pragma unroll
        for (int oi = 0; oi < 8; ++oi)
            ob[n * CDIM + obase + oi] = acc[oi][ni] * s[oi] + t[oi];
    }
}

// ---------------------------------------------------------------------------
extern "C" void kernel_launch(void* const* d_in, const int* in_sizes, int n_in,
                              void* d_out, int out_size, void* d_ws, size_t ws_size,
                              hipStream_t stream) {
    const float* x      = (const float*)d_in[0];
    const float* qkv_w  = (const float*)d_in[1];
    const float* qkv_g  = (const float*)d_in[2];
    const float* qkv_b  = (const float*)d_in[3];
    const float* qkv_m  = (const float*)d_in[4];
    const float* qkv_v  = (const float*)d_in[5];
    const float* dw_w   = (const float*)d_in[6];
    const float* dw_g   = (const float*)d_in[7];
    const float* dw_b   = (const float*)d_in[8];
    const float* dw_m   = (const float*)d_in[9];
    const float* dw_v   = (const float*)d_in[10];
    const float* proj_w = (const float*)d_in[11];
    const float* proj_g = (const float*)d_in[12];
    const float* proj_b = (const float*)d_in[13];
    const float* proj_m = (const float*)d_in[14];
    const float* proj_v = (const float*)d_in[15];
    const float* attn_bias = (const float*)d_in[16];
    const int*   bias_idxs = (const int*)d_in[17];
    float* out = (float*)d_out;

    hipLaunchKernelGGL(cga_attn_kernel, dim3(BATCH), dim3(256), 0, stream,
        x, qkv_w, qkv_g, qkv_b, qkv_m, qkv_v,
        dw_w, dw_g, dw_b, dw_m, dw_v, attn_bias, bias_idxs, out);
    hipLaunchKernelGGL(cga_proj_kernel, dim3(BATCH), dim3(256), 0, stream,
        proj_w, proj_g, proj_b, proj_m, proj_v, out);
}

// Round 3
// 2041.959 us; speedup vs baseline: 2.0952x; 2.0952x over previous
//
#include <hip/hip_runtime.h>
#include <hip/hip_bf16.h>

#define BATCH 2048
#define RES   7
#define NPOS  49
#define CDIM  512
#define HEADS 4
#define KD    32
#define DDIM  128
#define QO    192
#define EPS   1e-5f
#define KPAD  33

typedef __attribute__((ext_vector_type(8))) short short8;   // 8 bf16 (4 VGPRs)
typedef __attribute__((ext_vector_type(4))) float floatx4;  // 4 fp32 acc

// NOTE (R2 lesson): do NOT use d_ws — writing 512 KB there corrupted the
// harness's pristine input copies (ws_size is evidently small). All scratch
// lives in LDS / registers / d_out.

__device__ inline short8 pack_bf16x8(float4 a, float4 b) {
    union { short8 s; __hip_bfloat162 h[4]; } u;
    u.h[0] = __float22bfloat162_rn(make_float2(a.x, a.y));
    u.h[1] = __float22bfloat162_rn(make_float2(a.z, a.w));
    u.h[2] = __float22bfloat162_rn(make_float2(b.x, b.y));
    u.h[3] = __float22bfloat162_rn(make_float2(b.z, b.w));
    return u.s;
}

// ---------------------------------------------------------------------------
// Kernel 1: cascaded group attention (unchanged, passed R1). One block/batch.
// Writes RAW (pre-relu) head outputs into d_out at h[b][n][head*128+d].
// ---------------------------------------------------------------------------
__global__ __launch_bounds__(256) void cga_attn_kernel(
    const float* __restrict__ x,
    const float* __restrict__ qkv_w,
    const float* __restrict__ qkv_g, const float* __restrict__ qkv_bb,
    const float* __restrict__ qkv_m, const float* __restrict__ qkv_v,
    const float* __restrict__ dw_w,
    const float* __restrict__ dw_g, const float* __restrict__ dw_bb,
    const float* __restrict__ dw_m, const float* __restrict__ dw_v,
    const float* __restrict__ attn_bias,
    const int*   __restrict__ bias_idxs,
    float* __restrict__ hout)
{
    __shared__ float feat[NPOS * DDIM];
    __shared__ float qb  [NPOS * KD];
    __shared__ float kb  [NPOS * KPAD];
    __shared__ float vb  [NPOS * DDIM];
    __shared__ float qc  [NPOS * KD];
    __shared__ float att [NPOS * NPOS];

    const int b   = blockIdx.x;
    const int tid = threadIdx.x;
    const float scale = 0.17677669529663687f;
    const float* xb = x    + (size_t)b * NPOS * CDIM;
    float*       hb = hout + (size_t)b * NPOS * CDIM;

    for (int head = 0; head < HEADS; ++head) {
        for (int idx = tid; idx < NPOS * DDIM; idx += 256) {
            int n = idx >> 7, c = idx & 127;
            float xv = xb[n * CDIM + head * DDIM + c];
            feat[idx] = (head == 0) ? xv : feat[idx] + xv;
        }
        __syncthreads();

        if (tid < QO) {
            const int o = tid;
            const float4* wr = (const float4*)(qkv_w + (size_t)(head * QO + o) * DDIM);
            float acc[NPOS];
            #pragma unroll
            for (int n = 0; n < NPOS; ++n) acc[n] = 0.f;
            for (int d4 = 0; d4 < DDIM / 4; ++d4) {
                float4 w = wr[d4];
                #pragma unroll
                for (int n = 0; n < NPOS; ++n) {
                    float4 f = *(const float4*)(feat + n * DDIM + d4 * 4);
                    acc[n] += f.x * w.x + f.y * w.y + f.z * w.z + f.w * w.w;
                }
            }
            float s = qkv_g[head * QO + o] * rsqrtf(qkv_v[head * QO + o] + EPS);
            float t = qkv_bb[head * QO + o] - qkv_m[head * QO + o] * s;
            #pragma unroll
            for (int n = 0; n < NPOS; ++n) {
                float yv = acc[n] * s + t;
                if (o < KD)            qb[n * KD   + o]          = yv;
                else if (o < 2 * KD)   kb[n * KPAD + (o - KD)]   = yv;
                else                   vb[n * DDIM + (o - 2*KD)] = yv;
            }
        }
        __syncthreads();

        for (int idx = tid; idx < NPOS * KD; idx += 256) {
            int n = idx >> 5, ch = idx & 31;
            int r = n / RES, c0 = n - r * RES;
            const float* wd = dw_w + (size_t)(head * KD + ch) * 25;
            float acc = 0.f;
            #pragma unroll
            for (int dy = 0; dy < 5; ++dy) {
                int ry = r + dy - 2;
                if (ry < 0 || ry >= RES) continue;
                #pragma unroll
                for (int dx = 0; dx < 5; ++dx) {
                    int cx = c0 + dx - 2;
                    if (cx < 0 || cx >= RES) continue;
                    acc += qb[(ry * RES + cx) * KD + ch] * wd[dy * 5 + dx];
                }
            }
            float s = dw_g[head * KD + ch] * rsqrtf(dw_v[head * KD + ch] + EPS);
            float t = dw_bb[head * KD + ch] - dw_m[head * KD + ch] * s;
            qc[idx] = acc * s + t;
        }
        __syncthreads();

        for (int idx = tid; idx < NPOS * NPOS; idx += 256) {
            int n = idx / NPOS, m = idx - n * NPOS;
            float acc = 0.f;
            #pragma unroll
            for (int j = 0; j < KD; ++j) acc += qc[n * KD + j] * kb[m * KPAD + j];
            att[idx] = acc * scale + attn_bias[head * NPOS + bias_idxs[idx]];
        }
        __syncthreads();

        if (tid < NPOS) {
            float mx = -1e30f;
            for (int m = 0; m < NPOS; ++m) mx = fmaxf(mx, att[tid * NPOS + m]);
            float sm = 0.f;
            for (int m = 0; m < NPOS; ++m) {
                float e = __expf(att[tid * NPOS + m] - mx);
                att[tid * NPOS + m] = e;
                sm += e;
            }
            float inv = 1.f / sm;
            for (int m = 0; m < NPOS; ++m) att[tid * NPOS + m] *= inv;
        }
        __syncthreads();

        for (int idx = tid; idx < NPOS * (DDIM / 4); idx += 256) {
            int n = idx >> 5, d4 = idx & 31;
            float4 acc = {0.f, 0.f, 0.f, 0.f};
            for (int m = 0; m < NPOS; ++m) {
                float a = att[n * NPOS + m];
                float4 v4 = *(const float4*)(vb + m * DDIM + d4 * 4);
                acc.x += a * v4.x; acc.y += a * v4.y;
                acc.z += a * v4.z; acc.w += a * v4.w;
            }
            *(float4*)(feat + n * DDIM + d4 * 4) = acc;
            *(float4*)(hb + n * CDIM + head * DDIM + d4 * 4) = acc;
        }
        __syncthreads();
    }
}

// ---------------------------------------------------------------------------
// Kernel 2: out = BN(relu(h) @ proj_w^T) via bf16 MFMA, in place on d_out.
// Each block owns 32 complete M-rows (100352 = 32*3136) -> race-free in-place.
// B-fragments loaded as fp32 from proj_w (L2-resident) and converted to bf16
// in-register each K-step — no d_ws usage.
// ---------------------------------------------------------------------------
#define AROW 520   // LDS row stride (bf16 elems); rows 16B-aligned, pad never read

__global__ __launch_bounds__(256) void proj_mfma_kernel(
    const float* __restrict__ pw,    // [512 out][512 in] fp32
    const float* __restrict__ proj_g, const float* __restrict__ proj_bb,
    const float* __restrict__ proj_m, const float* __restrict__ proj_v,
    float* __restrict__ io)
{
    __shared__ unsigned short As[32 * AROW];   // 33280 B

    const int tid = threadIdx.x;
    const int m0  = blockIdx.x * 32;

    // ---- stage 32 rows: fp32 -> relu -> bf16 (RNE) into LDS
    for (int it = tid; it < 32 * 128; it += 256) {
        int r = it >> 7, c4 = it & 127;
        float4 vv = *(const float4*)(io + (size_t)(m0 + r) * CDIM + c4 * 4);
        vv.x = fmaxf(vv.x, 0.f); vv.y = fmaxf(vv.y, 0.f);
        vv.z = fmaxf(vv.z, 0.f); vv.w = fmaxf(vv.w, 0.f);
        __hip_bfloat162 p0 = __float22bfloat162_rn(make_float2(vv.x, vv.y));
        __hip_bfloat162 p1 = __float22bfloat162_rn(make_float2(vv.z, vv.w));
        unsigned short* dst = As + r * AROW + c4 * 4;
        *reinterpret_cast<__hip_bfloat162*>(dst)     = p0;
        *reinterpret_cast<__hip_bfloat162*>(dst + 2) = p1;
    }
    __syncthreads();

    const int wave  = tid >> 6;
    const int lane  = tid & 63;
    const int quad  = lane >> 4;
    const int l15   = lane & 15;
    const int nbase = wave * 128;

    floatx4 acc[2][8];
    #pragma unroll
    for (int mt = 0; mt < 2; ++mt)
        #pragma unroll
        for (int nt = 0; nt < 8; ++nt)
            acc[mt][nt] = (floatx4){0.f, 0.f, 0.f, 0.f};

    // A frag: A[m = mt*16 + l15][k = quad*8 + j]
    const unsigned short* a0p = As + (0  + l15) * AROW + quad * 8;
    const unsigned short* a1p = As + (16 + l15) * AROW + quad * 8;
    // B frag: W[n = nbase + nt*16 + l15][k = quad*8 + j], fp32 source
    const float* bpf = pw + (size_t)(nbase + l15) * CDIM + quad * 8;

    for (int k0 = 0; k0 < CDIM; k0 += 32) {
        short8 afr0 = *(const short8*)(a0p + k0);
        short8 afr1 = *(const short8*)(a1p + k0);
        short8 bfr[8];
        #pragma unroll
        for (int nt = 0; nt < 8; ++nt) {
            const float* wp = bpf + (size_t)nt * 16 * CDIM + k0;
            float4 w0 = *(const float4*)(wp);
            float4 w1 = *(const float4*)(wp + 4);
            bfr[nt] = pack_bf16x8(w0, w1);
        }
        #pragma unroll
        for (int nt = 0; nt < 8; ++nt) {
            acc[0][nt] = __builtin_amdgcn_mfma_f32_16x16x32_bf16(afr0, bfr[nt], acc[0][nt], 0, 0, 0);
            acc[1][nt] = __builtin_amdgcn_mfma_f32_16x16x32_bf16(afr1, bfr[nt], acc[1][nt], 0, 0, 0);
        }
    }

    // ---- BN epilogue. C/D layout: col = lane&15 (n), row = quad*4 + reg (m).
    float sc[8], tb[8];
    #pragma unroll
    for (int nt = 0; nt < 8; ++nt) {
        int o = nbase + nt * 16 + l15;
        sc[nt] = proj_g[o] * rsqrtf(proj_v[o] + EPS);
        tb[nt] = proj_bb[o] - proj_m[o] * sc[nt];
    }
    #pragma unroll
    for (int mt = 0; mt < 2; ++mt) {
        #pragma unroll
        for (int r = 0; r < 4; ++r) {
            int row = m0 + mt * 16 + quad * 4 + r;
            float* orow = io + (size_t)row * CDIM + nbase + l15;
            #pragma unroll
            for (int nt = 0; nt < 8; ++nt)
                orow[nt * 16] = acc[mt][nt][r] * sc[nt] + tb[nt];
        }
    }
}

// ---------------------------------------------------------------------------
extern "C" void kernel_launch(void* const* d_in, const int* in_sizes, int n_in,
                              void* d_out, int out_size, void* d_ws, size_t ws_size,
                              hipStream_t stream) {
    const float* x      = (const float*)d_in[0];
    const float* qkv_w  = (const float*)d_in[1];
    const float* qkv_g  = (const float*)d_in[2];
    const float* qkv_b  = (const float*)d_in[3];
    const float* qkv_m  = (const float*)d_in[4];
    const float* qkv_v  = (const float*)d_in[5];
    const float* dw_w   = (const float*)d_in[6];
    const float* dw_g   = (const float*)d_in[7];
    const float* dw_b   = (const float*)d_in[8];
    const float* dw_m   = (const float*)d_in[9];
    const float* dw_v   = (const float*)d_in[10];
    const float* proj_w = (const float*)d_in[11];
    const float* proj_g = (const float*)d_in[12];
    const float* proj_b = (const float*)d_in[13];
    const float* proj_m = (const float*)d_in[14];
    const float* proj_v = (const float*)d_in[15];
    const float* attn_bias = (const float*)d_in[16];
    const int*   bias_idxs = (const int*)d_in[17];
    float* out = (float*)d_out;
    (void)d_ws; (void)ws_size;   // R2 lesson: d_ws is too small for 512 KB; unused.

    hipLaunchKernelGGL(cga_attn_kernel, dim3(BATCH), dim3(256), 0, stream,
        x, qkv_w, qkv_g, qkv_b, qkv_m, qkv_v,
        dw_w, dw_g, dw_b, dw_m, dw_v, attn_bias, bias_idxs, out);
    hipLaunchKernelGGL(proj_mfma_kernel, dim3(100352 / 32), dim3(256), 0, stream,
        proj_w, proj_g, proj_b, proj_m, proj_v, out);
}